// Round 2
// baseline (1753.133 us; speedup 1.0000x reference)
//
#include <hip/hip_runtime.h>

// 2-layer stacked LSTM: B=256, T=2048, H=64, layer2 hidden=1.
//
// Round-5 restructure: ONE WAVE per batch element (256 blocks x 64 threads).
// Lane l owns layer-1 unit l and computes ALL FOUR of its gates; the 65x256
// layer-1 weight panel is distributed as 256 f32 per lane, held in VGPRs as
// f32x2 pairs so the backend can select v_pk_fma_f32 (packed fp32, gfx90a+).
// Why: rounds 0-1 showed VGPR_Count=56..64 -> W1 was NEVER register-resident
// with 5-wave blocks (waves_per_eu(1) is unsatisfiable at 5 waves/block), and
// the per-step barrier + cross-wave exchange cost ~800cy/step that no LDS/
// store micro-fix touched. Single-wave design:
//   - zero __syncthreads: same-wave DS ops are in-order, so the h1
//     ds_write -> next-step ds_read round trip needs no barrier;
//   - clean 512-VGPR budget (1 wave/block + waves_per_eu(1));
//   - layer 2 in the same wave, split head/tail around the step boundary:
//     head = 4 products + 4-level DPP row-reduce (VALU only), tail (next
//     iteration) = 16 v_readlane cross-row combine + activations, which
//     executes while the next step's 17 LDS reads are in flight.
constexpr int kT = 2048;
constexpr int kB = 256;
constexpr int kH = 64;

typedef __attribute__((ext_vector_type(2))) float f32x2;
typedef __attribute__((ext_vector_type(4))) float f32x4;

__device__ __forceinline__ float fast_sig(float x) {
    return __builtin_amdgcn_rcpf(1.0f + __expf(-x));
}
__device__ __forceinline__ float fast_tanh(float x) {
    float t = __expf(2.0f * x);
    return 1.0f - 2.0f * __builtin_amdgcn_rcpf(t + 1.0f);
}
__device__ __forceinline__ float rl(float v, int lane) {
    return __int_as_float(__builtin_amdgcn_readlane(__float_as_int(v), lane));
}
// One butterfly level as a DPP add (VALU pipe, no LDS).
template <int CTRL>
__device__ __forceinline__ float dpp_add(float v) {
    int t = __builtin_amdgcn_update_dpp(0, __float_as_int(v), CTRL, 0xF, 0xF, true);
    return v + __int_as_float(t);
}
// All 16 lanes of each row end with the row sum.
__device__ __forceinline__ float row_reduce16(float v) {
    v = dpp_add<0xB1>(v);   // quad_perm [1,0,3,2]  (xor 1)
    v = dpp_add<0x4E>(v);   // quad_perm [2,3,0,1]  (xor 2)
    v = dpp_add<0x141>(v);  // row_half_mirror      (8-group sum)
    v = dpp_add<0x140>(v);  // row_mirror           (16-group sum)
    return v;
}

__global__ __launch_bounds__(64)
__attribute__((amdgpu_waves_per_eu(1)))
void lstm2_kernel(
    const float* __restrict__ x, const float* __restrict__ W1,
    const float* __restrict__ b1, const float* __restrict__ W2,
    const float* __restrict__ b2, float* __restrict__ out)
{
    __shared__ f32x4 x4_lds[kT / 4];     // whole input row
    __shared__ f32x4 out4_lds[kT / 4];   // h2 staging, bulk-stored at the end
    __shared__ f32x4 h4_lds[kH / 4];     // h1(t-1), republished every step
    float* x_lds = (float*)x4_lds;
    float* out_lds = (float*)out4_lds;
    float* h_lds = (float*)h4_lds;

    const int l = threadIdx.x;           // lane == layer-1 unit id
    const int b = blockIdx.x;
    const f32x4* xg4 = (const f32x4*)(x + (size_t)b * kT);
    f32x4* outg4 = (f32x4*)(out + (size_t)b * kT);

    for (int i = l; i < kT / 4; i += 64) x4_lds[i] = xg4[i];
    h_lds[l] = 0.0f;

    // ---- per-lane weights: W1 columns for unit l, all 4 gates ----
    // wp[g][j] pairs with (h[2j], h[2j+1]); W1 row r+1 multiplies h[r].
    f32x2 wp[4][32];
    float w0g[4], bg[4], w2r[4];
    #pragma unroll
    for (int g = 0; g < 4; ++g) {
        const int col = g * 64 + l;      // gate-major: i, j, f, o quarters
        w0g[g] = W1[col];
        bg[g]  = b1[col];
        #pragma unroll
        for (int j = 0; j < 32; ++j) {
            wp[g][j].x = W1[(2 * j + 1) * 256 + col];
            wp[g][j].y = W1[(2 * j + 2) * 256 + col];
        }
        w2r[g] = W2[l * 4 + g];          // layer-2 weight for h1[l], gate g
    }
    f32x4 w2t = ((const f32x4*)W2)[kH];  // W2[64][0..3]: h2 recurrent row
    f32x4 b2v = ((const f32x4*)b2)[0];

    // ---- PIN loop invariants into registers (opaque RMW) ----
    #pragma unroll
    for (int g = 0; g < 4; ++g) {
        #pragma unroll
        for (int j = 0; j < 32; ++j) asm volatile("" : "+v"(wp[g][j]));
        asm volatile("" : "+v"(w0g[g]), "+v"(bg[g]), "+v"(w2r[g]));
    }
    asm volatile("" : "+v"(w2t), "+v"(b2v));

    float c1 = 0.0f, h1own = 0.0f, c2 = 0.0f, h2 = 0.0f;
    float r0 = 0.0f, r1 = 0.0f, r2 = 0.0f, r3 = 0.0f;  // staged row sums

    #pragma unroll 1
    for (int t = 0; t < kT; ++t) {
        // Issue this step's operand reads first. They sit behind last step's
        // h_lds write in the wave's in-order DS queue, so they observe
        // h1(t-1); their latency hides under the deferred layer-2 tail.
        const float xt = x_lds[t];
        f32x4 h4[16];
        #pragma unroll
        for (int k = 0; k < 16; ++k) h4[k] = h4_lds[k];

        // ---- layer-2 tail for step t-1: cross-row combine + activations ----
        if (t != 0) {
            const float zi = rl(r0,0)+rl(r0,16)+rl(r0,32)+rl(r0,48) + b2v.x + h2 * w2t.x;
            const float zj = rl(r1,0)+rl(r1,16)+rl(r1,32)+rl(r1,48) + b2v.y + h2 * w2t.y;
            const float zf = rl(r2,0)+rl(r2,16)+rl(r2,32)+rl(r2,48) + b2v.z + h2 * w2t.z;
            const float zo = rl(r3,0)+rl(r3,16)+rl(r3,32)+rl(r3,48) + b2v.w + h2 * w2t.w;
            c2 = fast_sig(zf + 1.0f) * c2 + fast_sig(zi) * fast_tanh(zj);
            h2 = fast_sig(zo) * fast_tanh(c2);
            if (l == 0) out_lds[t - 1] = h2;
        }

        // ---- layer-1: z[g] = b + x*w0 + sum_k h[k]*W[k], packed pairs ----
        f32x2 a0 = {fmaf(xt, w0g[0], bg[0]), 0.0f};
        f32x2 a1 = {fmaf(xt, w0g[1], bg[1]), 0.0f};
        f32x2 a2 = {fmaf(xt, w0g[2], bg[2]), 0.0f};
        f32x2 a3 = {fmaf(xt, w0g[3], bg[3]), 0.0f};
        #pragma unroll
        for (int k = 0; k < 16; ++k) {
            const f32x2 lo = h4[k].xy;
            const f32x2 hi = h4[k].zw;
            a0 += lo * wp[0][2*k]; a0 += hi * wp[0][2*k+1];
            a1 += lo * wp[1][2*k]; a1 += hi * wp[1][2*k+1];
            a2 += lo * wp[2][2*k]; a2 += hi * wp[2][2*k+1];
            a3 += lo * wp[3][2*k]; a3 += hi * wp[3][2*k+1];
        }
        const float gi = fast_sig (a0.x + a0.y);
        const float gj = fast_tanh(a1.x + a1.y);
        const float gf = fast_sig (a2.x + a2.y + 1.0f);   // forget bias
        const float go = fast_sig (a3.x + a3.y);
        c1 = fmaf(gf, c1, gi * gj);
        h1own = go * fast_tanh(c1);
        h_lds[l] = h1own;            // publish for t+1 (same-wave, in-order)

        // ---- layer-2 head: products + in-row DPP reduce (consumed at t+1) --
        r0 = row_reduce16(h1own * w2r[0]);
        r1 = row_reduce16(h1own * w2r[1]);
        r2 = row_reduce16(h1own * w2r[2]);
        r3 = row_reduce16(h1own * w2r[3]);
    }

    // ---- final layer-2 tail (t == kT) ----
    {
        const float zi = rl(r0,0)+rl(r0,16)+rl(r0,32)+rl(r0,48) + b2v.x + h2 * w2t.x;
        const float zj = rl(r1,0)+rl(r1,16)+rl(r1,32)+rl(r1,48) + b2v.y + h2 * w2t.y;
        const float zf = rl(r2,0)+rl(r2,16)+rl(r2,32)+rl(r2,48) + b2v.z + h2 * w2t.z;
        const float zo = rl(r3,0)+rl(r3,16)+rl(r3,32)+rl(r3,48) + b2v.w + h2 * w2t.w;
        c2 = fast_sig(zf + 1.0f) * c2 + fast_sig(zi) * fast_tanh(zj);
        h2 = fast_sig(zo) * fast_tanh(c2);
        if (l == 0) out_lds[kT - 1] = h2;
    }

    // ---- bulk coalesced store of the whole output row ----
    for (int i = l; i < kT / 4; i += 64) outg4[i] = out4_lds[i];
}

extern "C" void kernel_launch(void* const* d_in, const int* in_sizes, int n_in,
                              void* d_out, int out_size, void* d_ws, size_t ws_size,
                              hipStream_t stream) {
    const float* x  = (const float*)d_in[0];
    const float* W1 = (const float*)d_in[1];
    const float* b1 = (const float*)d_in[2];
    const float* W2 = (const float*)d_in[3];
    const float* b2 = (const float*)d_in[4];
    float* out = (float*)d_out;
    lstm2_kernel<<<kB, 64, 0, stream>>>(x, W1, b1, W2, b2, out);
}